// Round 8
// baseline (383.686 us; speedup 1.0000x reference)
//
#include <hip/hip_runtime.h>
#include <hip/hip_bf16.h>
#include <math.h>

// Shapes (fixed by the problem)
#define Bb   64
#define Nn   40
#define Ww   256
#define FIN  64
#define Hh   4
#define Dd   32
#define Cc   128
#define NT   7
#define FC   128
#define WT   61          // receptive field of the TCN stack
#define W0   195         // first needed global timestep (255-60)
#define PSTRIDE 520      // LDS panel stride (ushorts): 64 rows x 8 + 8 pad
#define HS2  132         // h_lds row stride (floats)

// gat_ln: 1 tau per block (small-LDS overlay -> 4 blocks/CU)
#define XPAN1 512        // xa panel stride (ushorts): 64 rows x 8
#define PREPB 193        // prep blocks prepended to the gat grid

// workspace layout (byte offsets). seq stored as split bf16 (hi+lo),
// global layout per row r: [16 panels][61 rows][8 ushorts]
#define SEQHI_OFF  0u
#define SEQ_BYTES  (448u * WT * Cc * 2u)             // 6,995,968 B
#define SEQLO_OFF  (SEQHI_OFF + SEQ_BYTES)
#define WBH_OFF    (SEQLO_OFF + SEQ_BYTES)           // conv w frag bf16 hi
#define WB_BYTES   (8u * 4u * 24u * 64u * 8u * 2u)   // 786,432 B
#define WBL_OFF    (WBH_OFF + WB_BYTES)
#define PSB_OFF    (WBL_OFF + WB_BYTES)              // f32 bias[8][128]
#define PSS_OFF    (PSB_OFF + 4096u)                 // f32 scale[8][128]
#define PSH_OFF    (PSS_OFF + 4096u)                 // f32 shift[8][128]
#define WPHASE_US  49152u                            // ushorts per phase in WBH/WBL

typedef __attribute__((ext_vector_type(8)))  short short8;
typedef __attribute__((ext_vector_type(16))) float f32x16;

// erf via Abramowitz-Stegun 7.1.26 (|err| <= 1.5e-7); validated r4-r7.
__device__ __forceinline__ float gelu_exact(float v) {
    const float z = v * 0.70710678118654752440f;
    const float a = fabsf(z);
    const float t = 1.0f / fmaf(0.3275911f, a, 1.0f);
    float p = fmaf(t, 1.061405429f, -1.453152027f);
    p = fmaf(t, p, 1.421413741f);
    p = fmaf(t, p, -0.284496736f);
    p = fmaf(t, p, 0.254829592f);
    p *= t;
    const float e = 1.0f - p * __expf(-a * a);
    const float erfv = copysignf(e, z);
    return 0.5f * v * (1.0f + erfv);
}
__device__ __forceinline__ float b2f(ushort u) {
    union { uint i; float f; } c; c.i = ((uint)u) << 16; return c.f;
}
__device__ __forceinline__ void split_bf16(float v, ushort& h, ushort& l) {
    __hip_bfloat16 bh = __float2bfloat16(v);
    float fh = __bfloat162float(bh);
    __hip_bfloat16 bl = __float2bfloat16(v - fh);
    h = *(ushort*)&bh; l = *(ushort*)&bl;
}

// ---------------------------------------------------------------------------
// Kernel 1 (merged): blocks 0..192 = prep (conv weight frags + BN fold);
// blocks 193.. = per (b, tau) GAT + LN. 1 tau/block, 37.5 KB LDS.
// ---------------------------------------------------------------------------
__global__ __launch_bounds__(256)
__attribute__((amdgpu_waves_per_eu(4)))
void gat_prep_kernel(
    const float* __restrict__ x, const float* __restrict__ adj,
    const float* __restrict__ gat_w,
    const float* __restrict__ a_src, const float* __restrict__ a_dst,
    const float* __restrict__ ln_g, const float* __restrict__ ln_b,
    const float* __restrict__ c1w, const float* __restrict__ c1b,
    const float* __restrict__ c2w, const float* __restrict__ c2b,
    const float* __restrict__ bn1s, const float* __restrict__ bn1b,
    const float* __restrict__ bn1m, const float* __restrict__ bn1v,
    const float* __restrict__ bn2s, const float* __restrict__ bn2b,
    const float* __restrict__ bn2m, const float* __restrict__ bn2v,
    char* __restrict__ ws,
    ushort* __restrict__ seq_hi, ushort* __restrict__ seq_lo)
{
    // pool: phase1 = xa_hi(8192 B) | xa_lo(8192 B)
    //       phase2 = e(1280 B) | attn(4480 B) | g(3584 B)   (overlaid)
    __shared__ __align__(16) char pool[2 * 8192];
    __shared__ __align__(16) float h_lds[Nn * HS2];

    const int tid = threadIdx.x;

    // ---------------- prep branch ----------------
    if (blockIdx.x < PREPB) {
        if (blockIdx.x < 192) {
            const int t = blockIdx.x * 256 + tid;       // [0, 49152)
            const int lane  = t & 63;
            const int kstep = (t >> 6) % 24;
            const int nt    = ((t >> 6) / 24) & 3;
            const int p     = (t >> 6) / 96;
            const int l = p >> 1, cv = p & 1;
            const int co = nt * 32 + (lane & 31);
            const float* wsrc = cv ? c2w : c1w;
            ushort* wbh = (ushort*)(ws + WBH_OFF);
            ushort* wbl = (ushort*)(ws + WBL_OFF);
#pragma unroll
            for (int j = 0; j < 8; ++j) {
                const int k  = kstep * 16 + ((lane >> 5) << 3) + j;
                const int kk = k >> 7, ci = k & 127;
                const float w = wsrc[((size_t)(l * Cc + co) * Cc + ci) * 3 + kk];
                ushort h, lo; split_bf16(w, h, lo);
                wbh[(size_t)t * 8 + j] = h;
                wbl[(size_t)t * 8 + j] = lo;
            }
        } else {
            float* psb = (float*)(ws + PSB_OFF);
            float* pss = (float*)(ws + PSS_OFF);
            float* psh = (float*)(ws + PSH_OFF);
            for (int idx = tid; idx < 1024; idx += 256) {
                const int p = idx >> 7, co = idx & 127;
                const int l = p >> 1, cv = p & 1;
                const int lc = l * Cc + co;
                const float s  = cv ? bn2s[lc] : bn1s[lc];
                const float bb = cv ? bn2b[lc] : bn1b[lc];
                const float m  = cv ? bn2m[lc] : bn1m[lc];
                const float vv = cv ? bn2v[lc] : bn1v[lc];
                const float cb = cv ? c2b[lc] : c1b[lc];
                const float scale = s * rsqrtf(vv + 1e-5f);
                pss[idx] = scale;
                psh[idx] = bb - m * scale;
                psb[idx] = cb;
            }
        }
        return;
    }

    // ---------------- GAT + LN branch ----------------
    ushort* xa_hi = (ushort*)pool;
    ushort* xa_lo = (ushort*)(pool + 8192);
    float* e_lds    = (float*)pool;                 // [s][n][h] 2*40*4 f32
    float* attn_lds = (float*)(pool + 1280);        // [7][4][40]
    float* g_lds    = (float*)(pool + 5760);        // [7][128]

    const int blk = blockIdx.x - PREPB;
    const int b   = blk / WT;
    const int tau = blk % WT;
    const int w   = W0 + tau;

    // ---- stage x[b,:,w,:] as bf16 hi/lo A-fragment panels ----
    for (int idx = tid; idx < Nn * 8; idx += 256) {
        const int n  = idx >> 3;
        const int oc = idx & 7;
        const float* src = x + ((size_t)(b * Nn + n) * Ww + w) * FIN + oc * 8;
        const float4 f0 = *(const float4*)(src);
        const float4 f1 = *(const float4*)(src + 4);
        ushort h[8], l[8];
        split_bf16(f0.x, h[0], l[0]); split_bf16(f0.y, h[1], l[1]);
        split_bf16(f0.z, h[2], l[2]); split_bf16(f0.w, h[3], l[3]);
        split_bf16(f1.x, h[4], l[4]); split_bf16(f1.y, h[5], l[5]);
        split_bf16(f1.z, h[6], l[6]); split_bf16(f1.w, h[7], l[7]);
        const int dst = oc * XPAN1 + n * 8;
        *(uint4*)(xa_hi + dst) = *(uint4*)h;
        *(uint4*)(xa_lo + dst) = *(uint4*)l;
    }
    __syncthreads();

    // ---- MFMA h-GEMM: wave nt -> co tile nt*32; 2 M-tiles ----
    {
        const int wave = tid >> 6;
        const int lane = tid & 63;
        const int nt   = wave;
        const int q2   = lane >> 5;
        const int m32  = lane & 31;
        const int co   = nt * 32 + m32;

        short8 BH[4], BL[4];
#pragma unroll
        for (int ks = 0; ks < 4; ++ks) {
            const float* gp = gat_w + co * FIN + ks * 16 + q2 * 8;
            const float4 f0 = *(const float4*)(gp);
            const float4 f1 = *(const float4*)(gp + 4);
            ushort h[8], l[8];
            split_bf16(f0.x, h[0], l[0]); split_bf16(f0.y, h[1], l[1]);
            split_bf16(f0.z, h[2], l[2]); split_bf16(f0.w, h[3], l[3]);
            split_bf16(f1.x, h[4], l[4]); split_bf16(f1.y, h[5], l[5]);
            split_bf16(f1.z, h[6], l[6]); split_bf16(f1.w, h[7], l[7]);
            BH[ks] = *(short8*)h;
            BL[ks] = *(short8*)l;
        }

#pragma unroll
        for (int mt = 0; mt < 2; ++mt) {
            f32x16 acc;
#pragma unroll
            for (int i = 0; i < 16; ++i) acc[i] = 0.f;
#pragma unroll
            for (int ks = 0; ks < 4; ++ks) {
                const int aoff = (ks * 2 + q2) * XPAN1 + (mt * 32 + m32) * 8;
                const short8 ah = *(const short8*)(xa_hi + aoff);
                const short8 al = *(const short8*)(xa_lo + aoff);
                acc = __builtin_amdgcn_mfma_f32_32x32x16_bf16(ah, BH[ks], acc, 0, 0, 0);
                acc = __builtin_amdgcn_mfma_f32_32x32x16_bf16(al, BH[ks], acc, 0, 0, 0);
                acc = __builtin_amdgcn_mfma_f32_32x32x16_bf16(ah, BL[ks], acc, 0, 0, 0);
            }
#pragma unroll
            for (int reg = 0; reg < 16; ++reg) {
                const int row = mt * 32 + (reg & 3) + 8 * (reg >> 2) + 4 * q2;
                if (row < Nn) h_lds[row * HS2 + co] = acc[reg];
            }
        }
    }
    __syncthreads();

    // ---- e_src/e_dst[n][h] = sum_d h[n][h*32+d] * a[h*32+d] ----
    for (int u = tid; u < 2 * Nn * Hh; u += 256) {
        const int s  = u & 1;
        const int hh = (u >> 1) & 3;
        const int n  = u >> 3;
        const float* av = (s ? a_dst : a_src) + hh * Dd;
        const float* hp = h_lds + n * HS2 + hh * Dd;
        float acc = 0.f;
#pragma unroll
        for (int i = 0; i < 8; ++i) {
            const float4 hv = *(const float4*)(hp + i * 4);
            const float4 avv = *(const float4*)(av + i * 4);
            acc += hv.x * avv.x + hv.y * avv.y + hv.z * avv.z + hv.w * avv.w;
        }
        e_lds[s * (Nn * Hh) + n * Hh + hh] = acc;
    }
    __syncthreads();

    // ---- attention softmax for target nodes n<7, all 4 heads ----
    if (tid < NT * Hh) {
        const int n  = tid >> 2;
        const int hh = tid & 3;
        const float es = e_lds[n * Hh + hh];
        float sc[Nn];
        float mx = -1e30f;
#pragma unroll
        for (int j = 0; j < Nn; ++j) {
            float s = es + e_lds[Nn * Hh + j * Hh + hh];
            s = (s > 0.f) ? s : 0.2f * s;
            if (adj[n * Nn + j] == 0.0f) s = -1e9f;
            sc[j] = s;
            mx = fmaxf(mx, s);
        }
        float sum = 0.f;
#pragma unroll
        for (int j = 0; j < Nn; ++j) { const float p = expf(sc[j] - mx); sc[j] = p; sum += p; }
        const float inv = 1.0f / sum;
#pragma unroll
        for (int j = 0; j < Nn; ++j)
            attn_lds[(n * Hh + hh) * Nn + j] = sc[j] * inv;
    }
    __syncthreads();

    // ---- gather: gat[n][c0..c0+3] = sum_j attn * h[j][c0..] ----
    if (tid < NT * 32) {
        const int n    = tid >> 5;
        const int cq   = tid & 31;
        const int c0   = cq * 4;
        const int head = cq >> 3;
        const float* ap = attn_lds + (n * Hh + head) * Nn;
        float4 acc = make_float4(0.f, 0.f, 0.f, 0.f);
        for (int j = 0; j < Nn; ++j) {
            const float a = ap[j];
            const float4 hv = *(const float4*)(h_lds + j * HS2 + c0);
            acc.x += a * hv.x; acc.y += a * hv.y;
            acc.z += a * hv.z; acc.w += a * hv.w;
        }
        *(float4*)(g_lds + n * Cc + c0) = acc;
    }
    __syncthreads();

    // ---- LayerNorm + write seq (K2 panel order) ----
    if (tid < NT * 32) {
        const int n = tid >> 5, lane = tid & 31;
        const float4 v = ((const float4*)(g_lds + n * Cc))[lane];
        float s  = v.x + v.y + v.z + v.w;
        float sq = v.x*v.x + v.y*v.y + v.z*v.z + v.w*v.w;
#pragma unroll
        for (int off = 16; off; off >>= 1) {
            s  += __shfl_xor(s, off, 32);
            sq += __shfl_xor(sq, off, 32);
        }
        const float mu   = s * (1.0f / Cc);
        const float rstd = rsqrtf(sq * (1.0f / Cc) - mu * mu + 1e-5f);
        const float4 gg = ((const float4*)ln_g)[lane];
        const float4 bb = ((const float4*)ln_b)[lane];
        float o0 = (v.x - mu) * rstd * gg.x + bb.x;
        float o1 = (v.y - mu) * rstd * gg.y + bb.y;
        float o2 = (v.z - mu) * rstd * gg.z + bb.z;
        float o3 = (v.w - mu) * rstd * gg.w + bb.w;
        const int r = b * NT + n;
        ushort4 uh, ul;
        split_bf16(o0, uh.x, ul.x);
        split_bf16(o1, uh.y, ul.y);
        split_bf16(o2, uh.z, ul.z);
        split_bf16(o3, uh.w, ul.w);
        const int p  = (lane >> 2) * 2 + ((lane >> 1) & 1);
        const int j0 = (lane & 1) * 4;
        const size_t off = ((size_t)(r * 16 + p) * WT + tau) * 8 + j0;
        *(ushort4*)(seq_hi + off) = uh;
        *(ushort4*)(seq_lo + off) = ul;
    }
}

// ---------------------------------------------------------------------------
// Kernel 2: per row r: TCN via split-bf16 MFMA.
// v8 = r4 structure (8 independent (mt,nt) waves, 8 barriers total, 6-deep
// weight prefetch, residual gather hoisted above the MFMA loop) with the
// VGPR cap lifted via waves_per_eu(4). r4's 173 us failure was a spill under
// the launch_bounds 64-VGPR cap (WRITE_SIZE 20.6->30.5 MB); r7 proved the
// attribute removes the cap (4-deep split-K >64 VGPR, no spill).
// ---------------------------------------------------------------------------
__device__ __forceinline__ void conv_mfma(
    const ushort* in_hi, const ushort* in_lo,
    ushort* out_hi, ushort* out_lo,
    const ushort* __restrict__ wbh, const ushort* __restrict__ wbl,
    const float* __restrict__ psb, const float* __restrict__ pss,
    const float* __restrict__ psh,
    const int tau0, const int d, const int mt, const int nt,
    const int lane, const bool residual)
{
    // M-tile [mt*32, mt*32+31] entirely below needed range -> nothing to do
    if (mt * 32 + 31 < tau0) return;

    const int m  = lane & 31;
    const int q2 = lane >> 5;
    const int co = nt * 32 + m;
    const int mbase = mt * 32 + m;

    const float bsv = psb[co], scv = pss[co], shv = psh[co];
    const int colb = ((co >> 4) * 2 + ((co >> 3) & 1)) * PSTRIDE + (co & 7);

    // hoisted residual gather: reads this wave's own pre-phase cells only
    // (written before the preceding barrier) -> overlaps the MFMA loop
    float rc[16];
    if (residual) {
#pragma unroll
        for (int reg = 0; reg < 16; ++reg) {
            const int row = (reg & 3) + 8 * (reg >> 2) + 4 * q2;
            const int tau = mt * 32 + row;
            const int off = colb + tau * 8;
            rc[reg] = (tau >= tau0 && tau <= 60)
                    ? (b2f(out_hi[off]) + b2f(out_lo[off])) : 0.f;
        }
    }

    // 3 distinct A-row indices (one per kernel tap kk)
    int rA0 = mbase - 2 * d; rA0 = rA0 < 0 ? 0 : rA0;
    int rA1 = mbase - d;     rA1 = rA1 < 0 ? 0 : rA1;
    const int rA2 = mbase;

    const ushort* wb_h = wbh + (size_t)(nt * 24) * 512 + lane * 8;
    const ushort* wb_l = wbl + (size_t)(nt * 24) * 512 + lane * 8;

    f32x16 acc0, acc1;
#pragma unroll
    for (int i = 0; i < 16; ++i) { acc0[i] = 0.f; acc1[i] = 0.f; }

    // 6-deep weight prefetch pipeline (48 VGPR; fits the lifted budget)
    short8 WH[6], WL[6];
#pragma unroll
    for (int i = 0; i < 6; ++i) {
        WH[i] = *(const short8*)(wb_h + i * 512);
        WL[i] = *(const short8*)(wb_l + i * 512);
    }

#pragma unroll
    for (int ks = 0; ks < 24; ++ks) {
        const int slot = ks % 6;
        const short8 bh = WH[slot];
        const short8 bl = WL[slot];
        if (ks + 6 < 24) {
            WH[slot] = *(const short8*)(wb_h + (ks + 6) * 512);
            WL[slot] = *(const short8*)(wb_l + (ks + 6) * 512);
        }
        const int kk   = ks >> 3;
        const int rowA = (kk == 0) ? rA0 : (kk == 1 ? rA1 : rA2);
        const int aoff = (((ks & 7) << 1) + q2) * PSTRIDE + rowA * 8;
        const short8 ah = *(const short8*)(in_hi + aoff);
        const short8 al = *(const short8*)(in_lo + aoff);
        // two interleaved dependency chains (36 + 36 instead of 72)
        acc0 = __builtin_amdgcn_mfma_f32_32x32x16_bf16(ah, bh, acc0, 0, 0, 0);
        acc1 = __builtin_amdgcn_mfma_f32_32x32x16_bf16(al, bh, acc1, 0, 0, 0);
        if (ks & 1)
            acc0 = __builtin_amdgcn_mfma_f32_32x32x16_bf16(ah, bl, acc0, 0, 0, 0);
        else
            acc1 = __builtin_amdgcn_mfma_f32_32x32x16_bf16(ah, bl, acc1, 0, 0, 0);
    }
#pragma unroll
    for (int i = 0; i < 16; ++i) acc0[i] += acc1[i];

#pragma unroll
    for (int reg = 0; reg < 16; ++reg) {
        const int row = (reg & 3) + 8 * (reg >> 2) + 4 * q2;
        const int tau = mt * 32 + row;
        if (tau >= tau0 && tau <= 60) {
            float v = (acc0[reg] + bsv) * scv + shv;
            v = gelu_exact(v);
            if (residual) v = gelu_exact(v + rc[reg]);
            ushort uh, ul; split_bf16(v, uh, ul);
            const int off = colb + tau * 8;
            out_hi[off] = uh; out_lo[off] = ul;
        }
    }
}

__global__ __launch_bounds__(512)
__attribute__((amdgpu_waves_per_eu(4)))
void tcn_head_kernel(
    const char* __restrict__ ws,
    const float* __restrict__ f1w, const float* __restrict__ f1b,
    const float* __restrict__ f2w, const float* __restrict__ f2b,
    float* __restrict__ out)
{
    __shared__ __align__(16) ushort cur_hi[16 * PSTRIDE];
    __shared__ __align__(16) ushort cur_lo[16 * PSTRIDE];
    __shared__ __align__(16) ushort o1_hi [16 * PSTRIDE];
    __shared__ __align__(16) ushort o1_lo [16 * PSTRIDE];
    __shared__ float red[FC];

    const int tid = threadIdx.x;
    const int r   = blockIdx.x;

    const ushort* seq_hi = (const ushort*)(ws + SEQHI_OFF);
    const ushort* seq_lo = (const ushort*)(ws + SEQLO_OFF);
    const ushort* WBH    = (const ushort*)(ws + WBH_OFF);
    const ushort* WBL    = (const ushort*)(ws + WBL_OFF);
    const float*  PSB    = (const float*)(ws + PSB_OFF);
    const float*  PSS    = (const float*)(ws + PSS_OFF);
    const float*  PSH    = (const float*)(ws + PSH_OFF);

    {
        const size_t base = (size_t)r * (16 * WT * 8);
        for (int i = tid; i < 16 * WT; i += 512) {
            const int p = i / WT, row = i - p * WT;
            const int dst = p * PSTRIDE + row * 8;
            *(uint4*)(cur_hi + dst) = *(const uint4*)(seq_hi + base + i * 8);
            *(uint4*)(cur_lo + dst) = *(const uint4*)(seq_lo + base + i * 8);
        }
    }
    __syncthreads();

    const int wave = tid >> 6;
    const int lane = tid & 63;
    const int nt   = wave & 3;
    const int mt   = wave >> 2;

    const int tau0_1[4] = {2, 8, 20, 44};
    const int tau0_2[4] = {4, 12, 28, 60};

#pragma unroll
    for (int l = 0; l < 4; ++l) {
        const int d  = 1 << l;
        const int p1 = 2 * l, p2 = 2 * l + 1;
        conv_mfma(cur_hi, cur_lo, o1_hi, o1_lo,
                  WBH + (size_t)p1 * WPHASE_US, WBL + (size_t)p1 * WPHASE_US,
                  PSB + p1 * Cc, PSS + p1 * Cc, PSH + p1 * Cc,
                  tau0_1[l], d, mt, nt, lane, false);
        __syncthreads();
        conv_mfma(o1_hi, o1_lo, cur_hi, cur_lo,
                  WBH + (size_t)p2 * WPHASE_US, WBL + (size_t)p2 * WPHASE_US,
                  PSB + p2 * Cc, PSS + p2 * Cc, PSH + p2 * Cc,
                  tau0_2[l], d, mt, nt, lane, true);
        __syncthreads();
    }

    // ---- fused head on cur row 60 ----
    if (tid < FC) {
        const float4* wr = (const float4*)(f1w + tid * Cc);
        float acc = 0.f;
#pragma unroll
        for (int i = 0; i < Cc / 4; ++i) {
            const float4 wv = wr[i];
            const int ci0 = i * 4;
            const int off = ((ci0 >> 4) * 2 + ((ci0 >> 3) & 1)) * PSTRIDE
                          + 60 * 8 + (ci0 & 7);
            const ushort4 vh = *(const ushort4*)(cur_hi + off);
            const ushort4 vl = *(const ushort4*)(cur_lo + off);
            acc += wv.x * (b2f(vh.x) + b2f(vl.x))
                 + wv.y * (b2f(vh.y) + b2f(vl.y))
                 + wv.z * (b2f(vh.z) + b2f(vl.z))
                 + wv.w * (b2f(vh.w) + b2f(vl.w));
        }
        red[tid] = gelu_exact(acc + f1b[tid]) * f2w[tid];
    }
    __syncthreads();
    if (tid < 64) {
        float v = red[tid] + red[tid + 64];
#pragma unroll
        for (int off = 32; off; off >>= 1) v += __shfl_xor(v, off, 64);
        if (tid == 0) out[r] = v + f2b[0];
    }
}

// ---------------------------------------------------------------------------
extern "C" void kernel_launch(void* const* d_in, const int* in_sizes, int n_in,
                              void* d_out, int out_size, void* d_ws, size_t ws_size,
                              hipStream_t stream) {
    const float* x     = (const float*)d_in[0];
    const float* adj   = (const float*)d_in[1];
    const float* gat_w = (const float*)d_in[2];
    const float* a_src = (const float*)d_in[3];
    const float* a_dst = (const float*)d_in[4];
    const float* ln_g  = (const float*)d_in[5];
    const float* ln_b  = (const float*)d_in[6];
    const float* c1w   = (const float*)d_in[7];
    const float* c1b   = (const float*)d_in[8];
    const float* c2w   = (const float*)d_in[9];
    const float* c2b   = (const float*)d_in[10];
    const float* bn1s  = (const float*)d_in[11];
    const float* bn1b  = (const float*)d_in[12];
    const float* bn1m  = (const float*)d_in[13];
    const float* bn1v  = (const float*)d_in[14];
    const float* bn2s  = (const float*)d_in[15];
    const float* bn2b  = (const float*)d_in[16];
    const float* bn2m  = (const float*)d_in[17];
    const float* bn2v  = (const float*)d_in[18];
    const float* f1w   = (const float*)d_in[19];
    const float* f1b   = (const float*)d_in[20];
    const float* f2w   = (const float*)d_in[21];
    const float* f2b   = (const float*)d_in[22];

    char* ws = (char*)d_ws;

    gat_prep_kernel<<<PREPB + Bb * WT, 256, 0, stream>>>(
        x, adj, gat_w, a_src, a_dst, ln_g, ln_b,
        c1w, c1b, c2w, c2b,
        bn1s, bn1b, bn1m, bn1v, bn2s, bn2b, bn2m, bn2v,
        ws, (ushort*)(ws + SEQHI_OFF), (ushort*)(ws + SEQLO_OFF));

    tcn_head_kernel<<<Bb * NT, 512, 0, stream>>>(
        ws, f1w, f1b, f2w, f2b, (float*)d_out);
}

// Round 9
// 363.778 us; speedup vs baseline: 1.0547x; 1.0547x over previous
//
#include <hip/hip_runtime.h>
#include <hip/hip_bf16.h>
#include <math.h>

// Shapes (fixed by the problem)
#define Bb   64
#define Nn   40
#define Ww   256
#define FIN  64
#define Hh   4
#define Dd   32
#define Cc   128
#define NT   7
#define FC   128
#define WT   61          // receptive field of the TCN stack
#define W0   195         // first needed global timestep (255-60)
#define PSTRIDE 520      // LDS panel stride (ushorts): 64 rows x 8 + 8 pad
#define HS2  132         // h_lds row stride (floats)

// gat_ln: 2 taus per block
#define GTAUS 2
#define NTG   31         // ceil(61/2)
#define XPAN  768        // xa panel stride (ushorts): 96 rows x 8
#define GROWS 80         // valid M rows (2 taus x 40 nodes)
#define PREPB 193        // prep blocks prepended to the gat grid

// workspace layout (byte offsets). seq stored as split bf16 (hi+lo),
// global layout per row r: [16 panels][61 rows][8 ushorts]
#define SEQHI_OFF  0u
#define SEQ_BYTES  (448u * WT * Cc * 2u)             // 6,995,968 B
#define SEQLO_OFF  (SEQHI_OFF + SEQ_BYTES)
#define WBH_OFF    (SEQLO_OFF + SEQ_BYTES)           // conv w frag bf16 hi
#define WB_BYTES   (8u * 4u * 24u * 64u * 8u * 2u)   // 786,432 B
#define WBL_OFF    (WBH_OFF + WB_BYTES)
#define PSB_OFF    (WBL_OFF + WB_BYTES)              // f32 bias[8][128]
#define PSS_OFF    (PSB_OFF + 4096u)                 // f32 scale[8][128]
#define PSH_OFF    (PSS_OFF + 4096u)                 // f32 shift[8][128]
#define WPHASE_US  49152u                            // ushorts per phase in WBH/WBL

typedef __attribute__((ext_vector_type(8)))  short short8;
typedef __attribute__((ext_vector_type(16))) float f32x16;

// erf via Abramowitz-Stegun 7.1.26 (|err| <= 1.5e-7); validated r4-r8.
__device__ __forceinline__ float gelu_exact(float v) {
    const float z = v * 0.70710678118654752440f;
    const float a = fabsf(z);
    const float t = 1.0f / fmaf(0.3275911f, a, 1.0f);
    float p = fmaf(t, 1.061405429f, -1.453152027f);
    p = fmaf(t, p, 1.421413741f);
    p = fmaf(t, p, -0.284496736f);
    p = fmaf(t, p, 0.254829592f);
    p *= t;
    const float e = 1.0f - p * __expf(-a * a);
    const float erfv = copysignf(e, z);
    return 0.5f * v * (1.0f + erfv);
}
__device__ __forceinline__ float b2f(ushort u) {
    union { uint i; float f; } c; c.i = ((uint)u) << 16; return c.f;
}
__device__ __forceinline__ void split_bf16(float v, ushort& h, ushort& l) {
    __hip_bfloat16 bh = __float2bfloat16(v);
    float fh = __bfloat162float(bh);
    __hip_bfloat16 bl = __float2bfloat16(v - fh);
    h = *(ushort*)&bh; l = *(ushort*)&bl;
}

// ---------------------------------------------------------------------------
// Kernel 1 (merged): blocks 0..192 = prep (conv weight frags + BN fold);
// blocks 193.. = per (b, tau-pair) GAT + LN. gat_w B-fragments are built
// in-kernel from global (no prep dependency) so prep overlaps the GAT work.
// ---------------------------------------------------------------------------
__global__ __launch_bounds__(256) void gat_prep_kernel(
    const float* __restrict__ x, const float* __restrict__ adj,
    const float* __restrict__ gat_w,
    const float* __restrict__ a_src, const float* __restrict__ a_dst,
    const float* __restrict__ ln_g, const float* __restrict__ ln_b,
    const float* __restrict__ c1w, const float* __restrict__ c1b,
    const float* __restrict__ c2w, const float* __restrict__ c2b,
    const float* __restrict__ bn1s, const float* __restrict__ bn1b,
    const float* __restrict__ bn1m, const float* __restrict__ bn1v,
    const float* __restrict__ bn2s, const float* __restrict__ bn2b,
    const float* __restrict__ bn2m, const float* __restrict__ bn2v,
    char* __restrict__ ws,
    ushort* __restrict__ seq_hi, ushort* __restrict__ seq_lo)
{
    // pool: phase1 = xa_hi(12288 B) | xa_lo(12288 B)
    //       phase2 = e(2560 B) | attn(8960 B) | g(7168 B)   (overlaid)
    __shared__ __align__(16) char pool[2 * 12288];
    __shared__ __align__(16) float h_lds[GROWS * HS2];

    const int tid = threadIdx.x;

    // ---------------- prep branch ----------------
    if (blockIdx.x < PREPB) {
        if (blockIdx.x < 192) {
            const int t = blockIdx.x * 256 + tid;       // [0, 49152)
            const int lane  = t & 63;
            const int kstep = (t >> 6) % 24;
            const int nt    = ((t >> 6) / 24) & 3;
            const int p     = (t >> 6) / 96;
            const int l = p >> 1, cv = p & 1;
            const int co = nt * 32 + (lane & 31);
            const float* wsrc = cv ? c2w : c1w;
            ushort* wbh = (ushort*)(ws + WBH_OFF);
            ushort* wbl = (ushort*)(ws + WBL_OFF);
#pragma unroll
            for (int j = 0; j < 8; ++j) {
                const int k  = kstep * 16 + ((lane >> 5) << 3) + j;
                const int kk = k >> 7, ci = k & 127;
                const float w = wsrc[((size_t)(l * Cc + co) * Cc + ci) * 3 + kk];
                ushort h, lo; split_bf16(w, h, lo);
                wbh[(size_t)t * 8 + j] = h;
                wbl[(size_t)t * 8 + j] = lo;
            }
        } else {
            float* psb = (float*)(ws + PSB_OFF);
            float* pss = (float*)(ws + PSS_OFF);
            float* psh = (float*)(ws + PSH_OFF);
            for (int idx = tid; idx < 1024; idx += 256) {
                const int p = idx >> 7, co = idx & 127;
                const int l = p >> 1, cv = p & 1;
                const int lc = l * Cc + co;
                const float s  = cv ? bn2s[lc] : bn1s[lc];
                const float bb = cv ? bn2b[lc] : bn1b[lc];
                const float m  = cv ? bn2m[lc] : bn1m[lc];
                const float vv = cv ? bn2v[lc] : bn1v[lc];
                const float cb = cv ? c2b[lc] : c1b[lc];
                const float scale = s * rsqrtf(vv + 1e-5f);
                pss[idx] = scale;
                psh[idx] = bb - m * scale;
                psb[idx] = cb;
            }
        }
        return;
    }

    // ---------------- GAT + LN branch ----------------
    ushort* xa_hi = (ushort*)pool;
    ushort* xa_lo = (ushort*)(pool + 12288);
    float* e_lds    = (float*)pool;                 // [tl][s][n][h] 2*2*40*4
    float* attn_lds = (float*)(pool + 2560);        // [tl][7][4][40]
    float* g_lds    = (float*)(pool + 11520);       // [tl][7][128]

    const int blk = blockIdx.x - PREPB;
    const int b   = blk / NTG;
    const int tg  = blk % NTG;
    const int tau0g  = tg * GTAUS;
    const int nvalid = (tau0g + 1 < WT) ? 2 : 1;

    // ---- stage x[b,:,w0..w0+1,:] as bf16 hi/lo A-fragment panels ----
    for (int idx = tid; idx < GTAUS * Nn * 8; idx += 256) {
        const int tl  = idx >= 320;
        const int rem = idx - tl * 320;
        const int n  = rem >> 3;
        const int oc = rem & 7;
        if (tl < nvalid) {
            const int w = W0 + tau0g + tl;
            const float* src = x + ((size_t)(b * Nn + n) * Ww + w) * FIN + oc * 8;
            const float4 f0 = *(const float4*)(src);
            const float4 f1 = *(const float4*)(src + 4);
            ushort h[8], l[8];
            split_bf16(f0.x, h[0], l[0]); split_bf16(f0.y, h[1], l[1]);
            split_bf16(f0.z, h[2], l[2]); split_bf16(f0.w, h[3], l[3]);
            split_bf16(f1.x, h[4], l[4]); split_bf16(f1.y, h[5], l[5]);
            split_bf16(f1.z, h[6], l[6]); split_bf16(f1.w, h[7], l[7]);
            const int dst = oc * XPAN + (tl * Nn + n) * 8;
            *(uint4*)(xa_hi + dst) = *(uint4*)h;
            *(uint4*)(xa_lo + dst) = *(uint4*)l;
        }
    }
    __syncthreads();

    // ---- MFMA h-GEMM: wave nt -> co tile nt*32; 3 M-tiles (rows 0..95,
    // garbage rows >= 80 feed discarded C rows only); B-frags from gat_w ----
    {
        const int wave = tid >> 6;
        const int lane = tid & 63;
        const int nt   = wave;
        const int q2   = lane >> 5;
        const int m32  = lane & 31;
        const int co   = nt * 32 + m32;

        short8 BH[4], BL[4];
#pragma unroll
        for (int ks = 0; ks < 4; ++ks) {
            const float* gp = gat_w + co * FIN + ks * 16 + q2 * 8;
            const float4 f0 = *(const float4*)(gp);
            const float4 f1 = *(const float4*)(gp + 4);
            ushort h[8], l[8];
            split_bf16(f0.x, h[0], l[0]); split_bf16(f0.y, h[1], l[1]);
            split_bf16(f0.z, h[2], l[2]); split_bf16(f0.w, h[3], l[3]);
            split_bf16(f1.x, h[4], l[4]); split_bf16(f1.y, h[5], l[5]);
            split_bf16(f1.z, h[6], l[6]); split_bf16(f1.w, h[7], l[7]);
            BH[ks] = *(short8*)h;
            BL[ks] = *(short8*)l;
        }

#pragma unroll
        for (int mt = 0; mt < 3; ++mt) {
            f32x16 acc;
#pragma unroll
            for (int i = 0; i < 16; ++i) acc[i] = 0.f;
#pragma unroll
            for (int ks = 0; ks < 4; ++ks) {
                const int aoff = (ks * 2 + q2) * XPAN + (mt * 32 + m32) * 8;
                const short8 ah = *(const short8*)(xa_hi + aoff);
                const short8 al = *(const short8*)(xa_lo + aoff);
                acc = __builtin_amdgcn_mfma_f32_32x32x16_bf16(ah, BH[ks], acc, 0, 0, 0);
                acc = __builtin_amdgcn_mfma_f32_32x32x16_bf16(al, BH[ks], acc, 0, 0, 0);
                acc = __builtin_amdgcn_mfma_f32_32x32x16_bf16(ah, BL[ks], acc, 0, 0, 0);
            }
#pragma unroll
            for (int reg = 0; reg < 16; ++reg) {
                const int row = mt * 32 + (reg & 3) + 8 * (reg >> 2) + 4 * q2;
                if (row < GROWS) h_lds[row * HS2 + co] = acc[reg];
            }
        }
    }
    __syncthreads();

    // ---- e_src/e_dst[tl][n][h] ----
    for (int u = tid; u < GTAUS * 2 * Nn * Hh; u += 256) {
        const int tl = u >= 320;
        const int uu = u - tl * 320;
        const int s  = uu & 1;
        const int hh = (uu >> 1) & 3;
        const int n  = uu >> 3;
        const float* av = (s ? a_dst : a_src) + hh * Dd;
        const float* hp = h_lds + (tl * Nn + n) * HS2 + hh * Dd;
        float acc = 0.f;
#pragma unroll
        for (int i = 0; i < 8; ++i) {
            const float4 hv = *(const float4*)(hp + i * 4);
            const float4 avv = *(const float4*)(av + i * 4);
            acc += hv.x * avv.x + hv.y * avv.y + hv.z * avv.z + hv.w * avv.w;
        }
        e_lds[((tl * 2 + s) * Nn + n) * Hh + hh] = acc;
    }
    __syncthreads();

    // ---- attention softmax for target nodes n<7 ----
    if (tid < GTAUS * NT * Hh) {
        const int tl = tid >= NT * Hh;
        const int i  = tid - tl * NT * Hh;
        const int n  = i >> 2;
        const int hh = i & 3;
        if (tl < nvalid) {
            const float es = e_lds[((tl * 2 + 0) * Nn + n) * Hh + hh];
            float sc[Nn];
            float mx = -1e30f;
#pragma unroll
            for (int j = 0; j < Nn; ++j) {
                float s = es + e_lds[((tl * 2 + 1) * Nn + j) * Hh + hh];
                s = (s > 0.f) ? s : 0.2f * s;
                if (adj[n * Nn + j] == 0.0f) s = -1e9f;
                sc[j] = s;
                mx = fmaxf(mx, s);
            }
            float sum = 0.f;
#pragma unroll
            for (int j = 0; j < Nn; ++j) { const float p = expf(sc[j] - mx); sc[j] = p; sum += p; }
            const float inv = 1.0f / sum;
#pragma unroll
            for (int j = 0; j < Nn; ++j)
                attn_lds[((tl * NT + n) * Hh + hh) * Nn + j] = sc[j] * inv;
        }
    }
    __syncthreads();

    // ---- gather ----
    for (int u = tid; u < GTAUS * NT * 32; u += 256) {
        const int tl = u >= NT * 32;
        const int i  = u - tl * NT * 32;
        const int n    = i >> 5;
        const int cq   = i & 31;
        const int c0   = cq * 4;
        const int head = cq >> 3;
        if (tl < nvalid) {
            const float* ap = attn_lds + ((tl * NT + n) * Hh + head) * Nn;
            float4 acc = make_float4(0.f, 0.f, 0.f, 0.f);
            for (int j = 0; j < Nn; ++j) {
                const float a = ap[j];
                const float4 hv = *(const float4*)(h_lds + (tl * Nn + j) * HS2 + c0);
                acc.x += a * hv.x; acc.y += a * hv.y;
                acc.z += a * hv.z; acc.w += a * hv.w;
            }
            *(float4*)(g_lds + (tl * NT + n) * Cc + c0) = acc;
        }
    }
    __syncthreads();

    // ---- LayerNorm + write seq (K2 panel order) ----
    for (int u = tid; u < GTAUS * NT * 32; u += 256) {
        const int tl = u >= NT * 32;
        const int i  = u - tl * NT * 32;
        const int n  = i >> 5;
        const int lane = u & 31;
        if (tl < nvalid) {
            const float4 v = ((const float4*)(g_lds + (tl * NT + n) * Cc))[lane];
            float s  = v.x + v.y + v.z + v.w;
            float sq = v.x*v.x + v.y*v.y + v.z*v.z + v.w*v.w;
#pragma unroll
            for (int off = 16; off; off >>= 1) {
                s  += __shfl_xor(s, off, 32);
                sq += __shfl_xor(sq, off, 32);
            }
            const float mu   = s * (1.0f / Cc);
            const float rstd = rsqrtf(sq * (1.0f / Cc) - mu * mu + 1e-5f);
            const float4 gg = ((const float4*)ln_g)[lane];
            const float4 bb = ((const float4*)ln_b)[lane];
            float o0 = (v.x - mu) * rstd * gg.x + bb.x;
            float o1 = (v.y - mu) * rstd * gg.y + bb.y;
            float o2 = (v.z - mu) * rstd * gg.z + bb.z;
            float o3 = (v.w - mu) * rstd * gg.w + bb.w;
            const int r = b * NT + n;
            const int tau = tau0g + tl;
            ushort4 uh, ul;
            split_bf16(o0, uh.x, ul.x);
            split_bf16(o1, uh.y, ul.y);
            split_bf16(o2, uh.z, ul.z);
            split_bf16(o3, uh.w, ul.w);
            const int p  = (lane >> 2) * 2 + ((lane >> 1) & 1);
            const int j0 = (lane & 1) * 4;
            const size_t off = ((size_t)(r * 16 + p) * WT + tau) * 8 + j0;
            *(ushort4*)(seq_hi + off) = uh;
            *(ushort4*)(seq_lo + off) = ul;
        }
    }
}

// ---------------------------------------------------------------------------
// Kernel 2: per row r: TCN via split-bf16 MFMA.
// v6 (split-K, best measured): wave = (nt, kh). Each wave covers ks in
// [kh*12, kh*12+12) for BOTH M-tiles -> per-wave weight loads halved,
// 12-iter loop covered by 3-deep prefetch (fits the compiler's pinned
// 64-VGPR budget; deeper pipelines spill — r4/r8). Cross-wave K-reduction
// through o1-as-f32-scratch (dead at exchange time for both c1 and c2).
// ---------------------------------------------------------------------------
__device__ __forceinline__ void conv_sk(
    const ushort* in_hi, const ushort* in_lo,
    ushort* out_hi, ushort* out_lo,
    float* scratch,                      // o1 pair as f32 (32 KB used)
    const ushort* __restrict__ wbh, const ushort* __restrict__ wbl,
    const float* __restrict__ psb, const float* __restrict__ pss,
    const float* __restrict__ psh,
    const int tau0, const int d, const int kh, const int nt,
    const int lane, const bool residual)
{
    const int m  = lane & 31;
    const int q2 = lane >> 5;
    const bool skipA = (tau0 > 31);      // tile A (rows 0..31) all discarded

    // A row indices per tap, both tiles (B never clamps: 32-2d >= 16)
    int rA0a = m - 2 * d; rA0a = rA0a < 0 ? 0 : rA0a;
    int rA1a = m - d;     rA1a = rA1a < 0 ? 0 : rA1a;
    const int rA2a = m;
    const int rA0b = 32 + m - 2 * d;
    const int rA1b = 32 + m - d;
    const int rA2b = 32 + m;

    const ushort* wb_h = wbh + (size_t)(nt * 24 + kh * 12) * 512 + lane * 8;
    const ushort* wb_l = wbl + (size_t)(nt * 24 + kh * 12) * 512 + lane * 8;

    const int co = nt * 32 + m;
    const float bsv = psb[co], scv = pss[co], shv = psh[co];
    const int colb = ((co >> 4) * 2 + ((co >> 3) & 1)) * PSTRIDE + (co & 7);

    f32x16 accA, accB;
#pragma unroll
    for (int i = 0; i < 16; ++i) { accA[i] = 0.f; accB[i] = 0.f; }

    // 3-deep weight prefetch (24 VGPR); window = 3 iters, covers L2 latency
    short8 WH[3], WL[3];
#pragma unroll
    for (int i = 0; i < 3; ++i) {
        WH[i] = *(const short8*)(wb_h + i * 512);
        WL[i] = *(const short8*)(wb_l + i * 512);
    }

#pragma unroll
    for (int i = 0; i < 12; ++i) {
        const int slot = i % 3;
        const short8 bh = WH[slot];
        const short8 bl = WL[slot];
        if (i + 3 < 12) {
            WH[slot] = *(const short8*)(wb_h + (i + 3) * 512);
            WL[slot] = *(const short8*)(wb_l + (i + 3) * 512);
        }
        const int ks = kh * 12 + i;
        const int kk = ks >> 3;
        const int panel = (((ks & 7) << 1) + q2) * PSTRIDE;
        if (!skipA) {
            const int ra = (kk == 0) ? rA0a : (kk == 1 ? rA1a : rA2a);
            const short8 ahA = *(const short8*)(in_hi + panel + ra * 8);
            const short8 alA = *(const short8*)(in_lo + panel + ra * 8);
            accA = __builtin_amdgcn_mfma_f32_32x32x16_bf16(ahA, bh, accA, 0, 0, 0);
            accA = __builtin_amdgcn_mfma_f32_32x32x16_bf16(alA, bh, accA, 0, 0, 0);
            accA = __builtin_amdgcn_mfma_f32_32x32x16_bf16(ahA, bl, accA, 0, 0, 0);
        }
        {
            const int rb = (kk == 0) ? rA0b : (kk == 1 ? rA1b : rA2b);
            const short8 ahB = *(const short8*)(in_hi + panel + rb * 8);
            const short8 alB = *(const short8*)(in_lo + panel + rb * 8);
            accB = __builtin_amdgcn_mfma_f32_32x32x16_bf16(ahB, bh, accB, 0, 0, 0);
            accB = __builtin_amdgcn_mfma_f32_32x32x16_bf16(alB, bh, accB, 0, 0, 0);
            accB = __builtin_amdgcn_mfma_f32_32x32x16_bf16(ahB, bl, accB, 0, 0, 0);
        }
    }

    // c2 (residual): scratch aliases in_* -> wait for all loop reads first.
    if (residual) __syncthreads();

    // exchange: wave (nt,kh) owns tile kh; writes the NON-owned partial.
    // slot layout: scratch[(tile*4+nt)*1024 + reg*64 + lane] (conflict-free)
    if (kh == 0) {
        float* dst = scratch + ((4 + nt) << 10) + lane;
#pragma unroll
        for (int r = 0; r < 16; ++r) dst[r * 64] = accB[r];
    } else if (!skipA) {
        float* dst = scratch + (nt << 10) + lane;
#pragma unroll
        for (int r = 0; r < 16; ++r) dst[r * 64] = accA[r];
    }
    __syncthreads();

    f32x16 acc;
    if (kh == 0) {
        acc = accA;
        if (!skipA) {
            const float* srcp = scratch + (nt << 10) + lane;
#pragma unroll
            for (int r = 0; r < 16; ++r) acc[r] += srcp[r * 64];
        }
    } else {
        acc = accB;
        const float* srcp = scratch + ((4 + nt) << 10) + lane;
#pragma unroll
        for (int r = 0; r < 16; ++r) acc[r] += srcp[r * 64];
    }

    // c1: epilogue writes land in o1 (= scratch) -> all reads must finish.
    if (!residual) __syncthreads();

    // epilogue for owned tile (mt = kh)
    if (!(skipA && kh == 0)) {
        const int mt = kh;
#pragma unroll
        for (int reg = 0; reg < 16; ++reg) {
            const int row = (reg & 3) + 8 * (reg >> 2) + 4 * q2;
            const int tau = mt * 32 + row;
            if (tau >= tau0 && tau <= 60) {
                float v = (acc[reg] + bsv) * scv + shv;
                v = gelu_exact(v);
                const int off = colb + tau * 8;
                if (residual)
                    v = gelu_exact(v + b2f(out_hi[off]) + b2f(out_lo[off]));
                ushort uh, ul; split_bf16(v, uh, ul);
                out_hi[off] = uh; out_lo[off] = ul;
            }
        }
    }
}

__global__ __launch_bounds__(512, 4) void tcn_head_kernel(
    const char* __restrict__ ws,
    const float* __restrict__ f1w, const float* __restrict__ f1b,
    const float* __restrict__ f2w, const float* __restrict__ f2b,
    float* __restrict__ out)
{
    __shared__ __align__(16) ushort cur_hi[16 * PSTRIDE];
    __shared__ __align__(16) ushort cur_lo[16 * PSTRIDE];
    __shared__ __align__(16) ushort o1_pair[2][16 * PSTRIDE];  // contiguous
    __shared__ float red[FC];

    ushort* o1_hi = o1_pair[0];
    ushort* o1_lo = o1_pair[1];
    float*  scratch = (float*)o1_pair;   // 33.3 KB >= 32 KB partial area

    const int tid = threadIdx.x;
    const int r   = blockIdx.x;

    const ushort* seq_hi = (const ushort*)(ws + SEQHI_OFF);
    const ushort* seq_lo = (const ushort*)(ws + SEQLO_OFF);
    const ushort* WBH    = (const ushort*)(ws + WBH_OFF);
    const ushort* WBL    = (const ushort*)(ws + WBL_OFF);
    const float*  PSB    = (const float*)(ws + PSB_OFF);
    const float*  PSS    = (const float*)(ws + PSS_OFF);
    const float*  PSH    = (const float*)(ws + PSH_OFF);

    {
        const size_t base = (size_t)r * (16 * WT * 8);
        for (int i = tid; i < 16 * WT; i += 512) {
            const int p = i / WT, row = i - p * WT;
            const int dst = p * PSTRIDE + row * 8;
            *(uint4*)(cur_hi + dst) = *(const uint4*)(seq_hi + base + i * 8);
            *(uint4*)(cur_lo + dst) = *(const uint4*)(seq_lo + base + i * 8);
        }
    }
    __syncthreads();

    const int wave = tid >> 6;
    const int lane = tid & 63;
    const int nt   = wave & 3;
    const int kh   = wave >> 2;

    const int tau0_1[4] = {2, 8, 20, 44};
    const int tau0_2[4] = {4, 12, 28, 60};

#pragma unroll
    for (int l = 0; l < 4; ++l) {
        const int d  = 1 << l;
        const int p1 = 2 * l, p2 = 2 * l + 1;
        conv_sk(cur_hi, cur_lo, o1_hi, o1_lo, scratch,
                WBH + (size_t)p1 * WPHASE_US, WBL + (size_t)p1 * WPHASE_US,
                PSB + p1 * Cc, PSS + p1 * Cc, PSH + p1 * Cc,
                tau0_1[l], d, kh, nt, lane, false);
        __syncthreads();
        conv_sk(o1_hi, o1_lo, cur_hi, cur_lo, scratch,
                WBH + (size_t)p2 * WPHASE_US, WBL + (size_t)p2 * WPHASE_US,
                PSB + p2 * Cc, PSS + p2 * Cc, PSH + p2 * Cc,
                tau0_2[l], d, kh, nt, lane, true);
        __syncthreads();
    }

    // ---- fused head on cur row 60 ----
    if (tid < FC) {
        const float4* wr = (const float4*)(f1w + tid * Cc);
        float acc = 0.f;
#pragma unroll
        for (int i = 0; i < Cc / 4; ++i) {
            const float4 wv = wr[i];
            const int ci0 = i * 4;
            const int off = ((ci0 >> 4) * 2 + ((ci0 >> 3) & 1)) * PSTRIDE
                          + 60 * 8 + (ci0 & 7);
            const ushort4 vh = *(const ushort4*)(cur_hi + off);
            const ushort4 vl = *(const ushort4*)(cur_lo + off);
            acc += wv.x * (b2f(vh.x) + b2f(vl.x))
                 + wv.y * (b2f(vh.y) + b2f(vl.y))
                 + wv.z * (b2f(vh.z) + b2f(vl.z))
                 + wv.w * (b2f(vh.w) + b2f(vl.w));
        }
        red[tid] = gelu_exact(acc + f1b[tid]) * f2w[tid];
    }
    __syncthreads();
    if (tid < 64) {
        float v = red[tid] + red[tid + 64];
#pragma unroll
        for (int off = 32; off; off >>= 1) v += __shfl_xor(v, off, 64);
        if (tid == 0) out[r] = v + f2b[0];
    }
}

// ---------------------------------------------------------------------------
extern "C" void kernel_launch(void* const* d_in, const int* in_sizes, int n_in,
                              void* d_out, int out_size, void* d_ws, size_t ws_size,
                              hipStream_t stream) {
    const float* x     = (const float*)d_in[0];
    const float* adj   = (const float*)d_in[1];
    const float* gat_w = (const float*)d_in[2];
    const float* a_src = (const float*)d_in[3];
    const float* a_dst = (const float*)d_in[4];
    const float* ln_g  = (const float*)d_in[5];
    const float* ln_b  = (const float*)d_in[6];
    const float* c1w   = (const float*)d_in[7];
    const float* c1b   = (const float*)d_in[8];
    const float* c2w   = (const float*)d_in[9];
    const float* c2b   = (const float*)d_in[10];
    const float* bn1s  = (const float*)d_in[11];
    const float* bn1b  = (const float*)d_in[12];
    const float* bn1m  = (const float*)d_in[13];
    const float* bn1v  = (const float*)d_in[14];
    const float* bn2s  = (const float*)d_in[15];
    const float* bn2b  = (const float*)d_in[16];
    const float* bn2m  = (const float*)d_in[17];
    const float* bn2v  = (const float*)d_in[18];
    const float* f1w   = (const float*)d_in[19];
    const float* f1b   = (const float*)d_in[20];
    const float* f2w   = (const float*)d_in[21];
    const float* f2b   = (const float*)d_in[22];

    char* ws = (char*)d_ws;

    gat_prep_kernel<<<PREPB + Bb * NTG, 256, 0, stream>>>(
        x, adj, gat_w, a_src, a_dst, ln_g, ln_b,
        c1w, c1b, c2w, c2b,
        bn1s, bn1b, bn1m, bn1v, bn2s, bn2b, bn2m, bn2v,
        ws, (ushort*)(ws + SEQHI_OFF), (ushort*)(ws + SEQLO_OFF));

    tcn_head_kernel<<<Bb * NT, 512, 0, stream>>>(
        ws, f1w, f1b, f2w, f2b, (float*)d_out);
}